// Round 2
// baseline (849.690 us; speedup 1.0000x reference)
//
#include <hip/hip_runtime.h>
#include <math.h>

#define N_PTS 20000
#define M_ATM 8000
#define DD    16
#define KK    16
#define HH    33
#define EPSGN 1e-5f
#define SLOPE 0.2f
#define LDS_CAP 4096

// ---------------- KNN: one block per point, f64 selection metric ----------------
__global__ __launch_bounds__(256) void knn_kernel(
    const float* __restrict__ x, const float* __restrict__ y,
    const int* __restrict__ xb, const int* __restrict__ yb,
    int* __restrict__ out_idx, float* __restrict__ out_d2)
{
    __shared__ double sdist[LDS_CAP];
    __shared__ double s_red_d[4];
    __shared__ int    s_red_i[4];

    const int n = blockIdx.x;
    const double x0 = (double)x[n*3+0], x1 = (double)x[n*3+1], x2 = (double)x[n*3+2];
    const int b = xb[n];

    // binary search range [lo, hi) in sorted y_batch
    int lo, hi;
    { int l = 0, r = M_ATM; while (l < r) { int m = (l+r) >> 1; if (yb[m] <  b) l = m+1; else r = m; } lo = l; }
    { int l = 0, r = M_ATM; while (l < r) { int m = (l+r) >> 1; if (yb[m] <= b) l = m+1; else r = m; } hi = l; }
    int cnt = hi - lo;
    if (cnt > LDS_CAP) cnt = LDS_CAP;  // never triggers for B=4, M=8000

    // f64 squared distances into LDS (true ordering => matches np/f64 ref top-k)
    for (int t = threadIdx.x; t < cnt; t += 256) {
        const int j = lo + t;
        const double d0 = x0 - (double)y[j*3+0];
        const double d1 = x1 - (double)y[j*3+1];
        const double d2 = x2 - (double)y[j*3+2];
        sdist[t] = d0*d0 + d1*d1 + d2*d2;
    }
    __syncthreads();

    const int lane = threadIdx.x & 63;
    const int wv   = threadIdx.x >> 6;
    const double INF = __builtin_inf();

    for (int r = 0; r < KK; ++r) {
        double best = INF;
        int    bi   = 0x7fffffff;
        for (int t = threadIdx.x; t < cnt; t += 256) {
            const double d = sdist[t];
            if (d < best) { best = d; bi = t; }
        }
        // wave (64-lane) reduce, tie -> lower index
        #pragma unroll
        for (int s = 32; s > 0; s >>= 1) {
            const double od = __shfl_down(best, s);
            const int    oi = __shfl_down(bi,   s);
            if (od < best || (od == best && oi < bi)) { best = od; bi = oi; }
        }
        if (lane == 0) { s_red_d[wv] = best; s_red_i[wv] = bi; }
        __syncthreads();
        if (threadIdx.x == 0) {
            double bd = s_red_d[0]; int bbi = s_red_i[0];
            #pragma unroll
            for (int w = 1; w < 4; ++w) {
                const double d = s_red_d[w]; const int i2 = s_red_i[w];
                if (d < bd || (d == bd && i2 < bbi)) { bd = d; bbi = i2; }
            }
            out_idx[n*KK + r] = lo + bbi;
            out_d2 [n*KK + r] = (float)bd;
            sdist[bbi] = INF;
        }
        __syncthreads();
    }
}

// ---------------- MP layers: 4 lanes per point ----------------
__global__ __launch_bounds__(256) void mp_kernel(
    const int*   __restrict__ nidx, const float* __restrict__ nd2,
    const float* __restrict__ yat,
    const float* __restrict__ W1, const float* __restrict__ b1,
    const float* __restrict__ W2, const float* __restrict__ b2,
    const float* __restrict__ gnw, const float* __restrict__ gnb,
    float* __restrict__ out)
{
    const int g  = blockIdx.x * 256 + threadIdx.x;
    const int n  = g >> 2;
    const int kl = g & 3;
    if (n >= N_PTS) return;

    // this lane's 4 neighbors
    const int4   iv = *reinterpret_cast<const int4*>  (nidx + n*KK + kl*4);
    const float4 dv = *reinterpret_cast<const float4*>(nd2  + n*KK + kl*4);
    const int   nb[4]   = { iv.x, iv.y, iv.z, iv.w };
    const float dist[4] = { dv.x, dv.y, dv.z, dv.w };

    float pe[DD];
    #pragma unroll
    for (int h = 0; h < DD; ++h) pe[h] = 1.0f;

    for (int L = 0; L < 3; ++L) {
        const float* w1  = W1 + L*HH*HH;   // [33][33] row o, col h
        const float* w2  = W2 + L*DD*HH;   // [16][33]
        const float* bb1 = b1 + L*HH;
        const float* bb2 = b2 + L*DD;

        // base[o] = b1[o] + sum_{h<16} pe[h] * W1[o][h]   (k-invariant part)
        float base[HH];
        #pragma unroll
        for (int o = 0; o < HH; ++o) {
            float t = bb1[o];
            #pragma unroll
            for (int h = 0; h < DD; ++h) t = fmaf(pe[h], w1[o*HH + h], t);
            base[o] = t;
        }

        float msg[DD];
        #pragma unroll
        for (int o = 0; o < DD; ++o) msg[o] = 4.0f * bb2[o];  // 4 k's per lane; x4 lanes = K*b2

        #pragma unroll
        for (int k = 0; k < 4; ++k) {
            const float4* ap = reinterpret_cast<const float4*>(yat + (long)nb[k]*DD);
            const float4 a0 = ap[0], a1 = ap[1], a2 = ap[2], a3 = ap[3];
            const float at[DD] = { a0.x,a0.y,a0.z,a0.w, a1.x,a1.y,a1.z,a1.w,
                                   a2.x,a2.y,a2.z,a2.w, a3.x,a3.y,a3.z,a3.w };
            float hk[HH];
            #pragma unroll
            for (int o = 0; o < HH; ++o) {
                float t = fmaf(dist[k], w1[o*HH + 32], base[o]);
                #pragma unroll
                for (int h = 0; h < DD; ++h) t = fmaf(at[h], w1[o*HH + 16 + h], t);
                hk[o] = fmaxf(t, SLOPE * t);   // leaky_relu
            }
            #pragma unroll
            for (int o = 0; o < DD; ++o) {
                float t = msg[o];
                #pragma unroll
                for (int h = 0; h < HH; ++h) t = fmaf(hk[h], w2[o*HH + h], t);
                msg[o] = t;
            }
        }

        // sum msg over the 4 lanes of this point
        #pragma unroll
        for (int o = 0; o < DD; ++o) {
            msg[o] += __shfl_xor(msg[o], 1);
            msg[o] += __shfl_xor(msg[o], 2);
        }

        // GroupNorm(2, 16) + leaky + residual (redundant per lane)
        #pragma unroll
        for (int grp = 0; grp < 2; ++grp) {
            float mu = 0.0f;
            #pragma unroll
            for (int j = 0; j < 8; ++j) mu += msg[grp*8 + j];
            mu *= 0.125f;
            float var = 0.0f;
            #pragma unroll
            for (int j = 0; j < 8; ++j) { const float d = msg[grp*8 + j] - mu; var = fmaf(d, d, var); }
            var *= 0.125f;
            const float rs = rsqrtf(var + EPSGN);
            #pragma unroll
            for (int j = 0; j < 8; ++j) {
                const int c = grp*8 + j;
                const float v = (msg[c] - mu) * rs * gnw[L*DD + c] + gnb[L*DD + c];
                pe[c] += fmaxf(v, SLOPE * v);
            }
        }
    }

    if (kl == 0) {
        float4* op = reinterpret_cast<float4*>(out + (long)n*DD);
        op[0] = make_float4(pe[0],  pe[1],  pe[2],  pe[3]);
        op[1] = make_float4(pe[4],  pe[5],  pe[6],  pe[7]);
        op[2] = make_float4(pe[8],  pe[9],  pe[10], pe[11]);
        op[3] = make_float4(pe[12], pe[13], pe[14], pe[15]);
    }
}

extern "C" void kernel_launch(void* const* d_in, const int* in_sizes, int n_in,
                              void* d_out, int out_size, void* d_ws, size_t ws_size,
                              hipStream_t stream) {
    const float* x   = (const float*)d_in[0];
    const float* y   = (const float*)d_in[1];
    const float* yat = (const float*)d_in[2];
    const int*   xb  = (const int*)  d_in[3];
    const int*   yb  = (const int*)  d_in[4];
    const float* W1  = (const float*)d_in[5];
    const float* b1  = (const float*)d_in[6];
    const float* W2  = (const float*)d_in[7];
    const float* b2  = (const float*)d_in[8];
    const float* gnw = (const float*)d_in[9];
    const float* gnb = (const float*)d_in[10];
    float* out = (float*)d_out;

    int*   ws_idx = (int*)d_ws;
    float* ws_d2  = (float*)((char*)d_ws + (size_t)N_PTS*KK*sizeof(int));

    knn_kernel<<<N_PTS, 256, 0, stream>>>(x, y, xb, yb, ws_idx, ws_d2);

    const int mp_threads = N_PTS * 4;
    mp_kernel<<<(mp_threads + 255) / 256, 256, 0, stream>>>(
        ws_idx, ws_d2, yat, W1, b1, W2, b2, gnw, gnb, out);
}

// Round 3
// 353.542 us; speedup vs baseline: 2.4034x; 2.4034x over previous
//
#include <hip/hip_runtime.h>
#include <math.h>

#define N_PTS 20000
#define M_ATM 8000
#define DD    16
#define KK    16
#define HH    33
#define EPSGN 1e-5f
#define SLOPE 0.2f
#define SLOTS 36   // 36*64 = 2304 candidates/wave >= max batch segment (2000 + 7.8 sigma)

// ---------------- KNN: one WAVE per point, no LDS, no barriers ----------------
// Exact f64 ordering (matches np/f64 reference top-k); tie-break smaller index.
__global__ __launch_bounds__(256) void knn_kernel(
    const float* __restrict__ x, const float* __restrict__ y,
    const int* __restrict__ xb, const int* __restrict__ yb,
    int* __restrict__ out_idx, float* __restrict__ out_d2)
{
    const int wv   = threadIdx.x >> 6;
    const int lane = threadIdx.x & 63;
    const int n    = blockIdx.x * 4 + wv;

    const double INF = __builtin_inf();
    const double x0 = (double)x[n*3+0], x1 = (double)x[n*3+1], x2 = (double)x[n*3+2];
    const int b = xb[n];

    int lo, hi;
    { int l = 0, r = M_ATM; while (l < r) { int m = (l+r) >> 1; if (yb[m] <  b) l = m+1; else r = m; } lo = l; }
    { int l = 0, r = M_ATM; while (l < r) { int m = (l+r) >> 1; if (yb[m] <= b) l = m+1; else r = m; } hi = l; }

    // per-lane candidate distances in registers (static indexing only)
    double cand[SLOTS];
    #pragma unroll
    for (int s = 0; s < SLOTS; ++s) {
        const int j = lo + lane + 64*s;
        if (j < hi) {
            const double d0 = x0 - (double)y[j*3+0];
            const double d1 = x1 - (double)y[j*3+1];
            const double d2 = x2 - (double)y[j*3+2];
            cand[s] = d0*d0 + d1*d1 + d2*d2;
        } else {
            cand[s] = INF;
        }
    }

    // per-lane (min, 2nd-min) with slots
    double m1 = INF, m2 = INF; int i1 = 0, i2 = 0;
    #pragma unroll
    for (int s = 0; s < SLOTS; ++s) {
        const double v = cand[s];
        if (v < m1)      { m2 = m1; i2 = i1; m1 = v; i1 = s; }
        else if (v < m2) { m2 = v;  i2 = s; }
    }

    unsigned long long cmask = 0ull;  // consumed-slot bitmask (per lane)
    bool has2 = true;
    int res_i = 0; float res_d = 0.0f;

    for (int r = 0; r < KK; ++r) {
        // wave argmin of (m1, key); key = slot*64+lane == global offset j-lo
        double bv = m1;
        int    bk = (i1 << 6) | lane;
        #pragma unroll
        for (int sft = 1; sft < 64; sft <<= 1) {
            const double ov = __shfl_xor(bv, sft);
            const int    ok = __shfl_xor(bk, sft);
            if (ov < bv || (ov == bv && ok < bk)) { bv = ov; bk = ok; }
        }

        if (lane == r) { res_i = lo + bk; res_d = (float)bv; }

        if (lane == (bk & 63)) {            // winner lane updates its state
            cmask |= (1ull << (bk >> 6));
            if (has2) {
                m1 = m2; i1 = i2; has2 = false;   // lazy promote
            } else {
                // rare: rebuild top-2 excluding consumed slots
                m1 = INF; m2 = INF; i1 = 0; i2 = 0;
                #pragma unroll
                for (int s = 0; s < SLOTS; ++s) {
                    const double v = ((cmask >> s) & 1ull) ? INF : cand[s];
                    if (v < m1)      { m2 = m1; i2 = i1; m1 = v; i1 = s; }
                    else if (v < m2) { m2 = v;  i2 = s; }
                }
                has2 = true;
            }
        }
    }

    if (lane < KK) {
        out_idx[n*KK + lane] = res_i;
        out_d2 [n*KK + lane] = res_d;
    }
}

// ---------------- MP layers: 8 lanes per point, 2 k's per lane ----------------
__global__ __launch_bounds__(256) void mp_kernel(
    const int*   __restrict__ nidx, const float* __restrict__ nd2,
    const float* __restrict__ yat,
    const float* __restrict__ W1, const float* __restrict__ b1,
    const float* __restrict__ W2, const float* __restrict__ b2,
    const float* __restrict__ gnw, const float* __restrict__ gnb,
    float* __restrict__ out)
{
    const int g  = blockIdx.x * 256 + threadIdx.x;
    const int n  = g >> 3;
    const int kl = g & 7;

    const int2   iv = *reinterpret_cast<const int2*>  (nidx + n*KK + kl*2);
    const float2 dv = *reinterpret_cast<const float2*>(nd2  + n*KK + kl*2);
    const int   nb[2]   = { iv.x, iv.y };
    const float dist[2] = { dv.x, dv.y };

    float pe[DD];
    #pragma unroll
    for (int h = 0; h < DD; ++h) pe[h] = 1.0f;

    for (int L = 0; L < 3; ++L) {
        const float* w1  = W1 + L*HH*HH;   // [33][33]
        const float* w2  = W2 + L*DD*HH;   // [16][33]
        const float* bb1 = b1 + L*HH;
        const float* bb2 = b2 + L*DD;

        // k-invariant part: base[o] = b1[o] + sum_h pe[h]*W1[o][h]
        float base[HH];
        #pragma unroll
        for (int o = 0; o < HH; ++o) {
            float t = bb1[o];
            #pragma unroll
            for (int h = 0; h < DD; ++h) t = fmaf(pe[h], w1[o*HH + h], t);
            base[o] = t;
        }

        float msg[DD];
        #pragma unroll
        for (int o = 0; o < DD; ++o) msg[o] = 2.0f * bb2[o];  // 2 k's/lane; x8 lanes = K*b2

        #pragma unroll
        for (int k = 0; k < 2; ++k) {
            const float4* ap = reinterpret_cast<const float4*>(yat + (long)nb[k]*DD);
            const float4 a0 = ap[0], a1 = ap[1], a2 = ap[2], a3 = ap[3];
            const float at[DD] = { a0.x,a0.y,a0.z,a0.w, a1.x,a1.y,a1.z,a1.w,
                                   a2.x,a2.y,a2.z,a2.w, a3.x,a3.y,a3.z,a3.w };
            // no hk[] array: fold W2 accumulation per hidden unit (keeps regs low)
            #pragma unroll
            for (int o = 0; o < HH; ++o) {
                float t = fmaf(dist[k], w1[o*HH + 32], base[o]);
                #pragma unroll
                for (int h = 0; h < DD; ++h) t = fmaf(at[h], w1[o*HH + 16 + h], t);
                const float hk = fmaxf(t, SLOPE * t);   // leaky_relu
                #pragma unroll
                for (int oo = 0; oo < DD; ++oo) msg[oo] = fmaf(hk, w2[oo*HH + o], msg[oo]);
            }
        }

        // sum msg over the 8 lanes of this point (contiguous lanes)
        #pragma unroll
        for (int o = 0; o < DD; ++o) {
            msg[o] += __shfl_xor(msg[o], 1);
            msg[o] += __shfl_xor(msg[o], 2);
            msg[o] += __shfl_xor(msg[o], 4);
        }

        // GroupNorm(2, 16) + leaky + residual (redundant per lane)
        #pragma unroll
        for (int grp = 0; grp < 2; ++grp) {
            float mu = 0.0f;
            #pragma unroll
            for (int j = 0; j < 8; ++j) mu += msg[grp*8 + j];
            mu *= 0.125f;
            float var = 0.0f;
            #pragma unroll
            for (int j = 0; j < 8; ++j) { const float d = msg[grp*8 + j] - mu; var = fmaf(d, d, var); }
            var *= 0.125f;
            const float rs = rsqrtf(var + EPSGN);
            #pragma unroll
            for (int j = 0; j < 8; ++j) {
                const int c = grp*8 + j;
                const float v = (msg[c] - mu) * rs * gnw[L*DD + c] + gnb[L*DD + c];
                pe[c] += fmaxf(v, SLOPE * v);
            }
        }
    }

    if (kl == 0) {
        float4* op = reinterpret_cast<float4*>(out + (long)n*DD);
        op[0] = make_float4(pe[0],  pe[1],  pe[2],  pe[3]);
        op[1] = make_float4(pe[4],  pe[5],  pe[6],  pe[7]);
        op[2] = make_float4(pe[8],  pe[9],  pe[10], pe[11]);
        op[3] = make_float4(pe[12], pe[13], pe[14], pe[15]);
    }
}

extern "C" void kernel_launch(void* const* d_in, const int* in_sizes, int n_in,
                              void* d_out, int out_size, void* d_ws, size_t ws_size,
                              hipStream_t stream) {
    const float* x   = (const float*)d_in[0];
    const float* y   = (const float*)d_in[1];
    const float* yat = (const float*)d_in[2];
    const int*   xb  = (const int*)  d_in[3];
    const int*   yb  = (const int*)  d_in[4];
    const float* W1  = (const float*)d_in[5];
    const float* b1  = (const float*)d_in[6];
    const float* W2  = (const float*)d_in[7];
    const float* b2  = (const float*)d_in[8];
    const float* gnw = (const float*)d_in[9];
    const float* gnb = (const float*)d_in[10];
    float* out = (float*)d_out;

    int*   ws_idx = (int*)d_ws;
    float* ws_d2  = (float*)((char*)d_ws + (size_t)N_PTS*KK*sizeof(int));

    // 4 independent waves (points) per block, no LDS, no barriers
    knn_kernel<<<N_PTS/4, 256, 0, stream>>>(x, y, xb, yb, ws_idx, ws_d2);

    // 8 lanes per point
    mp_kernel<<<(N_PTS*8)/256, 256, 0, stream>>>(
        ws_idx, ws_d2, yat, W1, b1, W2, b2, gnw, gnb, out);
}

// Round 4
// 191.742 us; speedup vs baseline: 4.4314x; 1.8438x over previous
//
#include <hip/hip_runtime.h>
#include <math.h>

#define N_PTS 20000
#define M_ATM 8000
#define DD    16
#define KK    16
#define HH    33
#define EPSGN 1e-5f
#define SLOPE 0.2f
#define SLOTS 36   // 36*64 = 2304 candidates/wave >= max batch segment

// packed layout per layer (floats): wx[33][20] | wb[33][16] | wt[33][16]
#define PK_WX   0
#define PK_WB   660
#define PK_WT   1188
#define PK_LAY  1716

// ---------------- KNN: one WAVE per point, no LDS, no barriers ----------------
__global__ __launch_bounds__(256) void knn_kernel(
    const float* __restrict__ x, const float* __restrict__ y,
    const int* __restrict__ xb, const int* __restrict__ yb,
    int* __restrict__ out_idx, float* __restrict__ out_d2)
{
    const int wv   = threadIdx.x >> 6;
    const int lane = threadIdx.x & 63;
    const int n    = blockIdx.x * 4 + wv;

    const double INF = __builtin_inf();
    const double x0 = (double)x[n*3+0], x1 = (double)x[n*3+1], x2 = (double)x[n*3+2];
    const int b = xb[n];

    int lo, hi;
    { int l = 0, r = M_ATM; while (l < r) { int m = (l+r) >> 1; if (yb[m] <  b) l = m+1; else r = m; } lo = l; }
    { int l = 0, r = M_ATM; while (l < r) { int m = (l+r) >> 1; if (yb[m] <= b) l = m+1; else r = m; } hi = l; }

    double cand[SLOTS];
    #pragma unroll
    for (int s = 0; s < SLOTS; ++s) {
        const int j = lo + lane + 64*s;
        if (j < hi) {
            const double d0 = x0 - (double)y[j*3+0];
            const double d1 = x1 - (double)y[j*3+1];
            const double d2 = x2 - (double)y[j*3+2];
            cand[s] = d0*d0 + d1*d1 + d2*d2;
        } else {
            cand[s] = INF;
        }
    }

    double m1 = INF, m2 = INF; int i1 = 0, i2 = 0;
    #pragma unroll
    for (int s = 0; s < SLOTS; ++s) {
        const double v = cand[s];
        if (v < m1)      { m2 = m1; i2 = i1; m1 = v; i1 = s; }
        else if (v < m2) { m2 = v;  i2 = s; }
    }

    unsigned long long cmask = 0ull;
    bool has2 = true;
    int res_i = 0; float res_d = 0.0f;

    for (int r = 0; r < KK; ++r) {
        double bv = m1;
        int    bk = (i1 << 6) | lane;
        #pragma unroll
        for (int sft = 1; sft < 64; sft <<= 1) {
            const double ov = __shfl_xor(bv, sft);
            const int    ok = __shfl_xor(bk, sft);
            if (ov < bv || (ov == bv && ok < bk)) { bv = ov; bk = ok; }
        }

        if (lane == r) { res_i = lo + bk; res_d = (float)bv; }

        if (lane == (bk & 63)) {
            cmask |= (1ull << (bk >> 6));
            if (has2) {
                m1 = m2; i1 = i2; has2 = false;
            } else {
                m1 = INF; m2 = INF; i1 = 0; i2 = 0;
                #pragma unroll
                for (int s = 0; s < SLOTS; ++s) {
                    const double v = ((cmask >> s) & 1ull) ? INF : cand[s];
                    if (v < m1)      { m2 = m1; i2 = i1; m1 = v; i1 = s; }
                    else if (v < m2) { m2 = v;  i2 = s; }
                }
                has2 = true;
            }
        }
    }

    if (lane < KK) {
        out_idx[n*KK + lane] = res_i;
        out_d2 [n*KK + lane] = res_d;
    }
}

// ---------------- weight repack into 16B-aligned rows ----------------
__global__ void repack_kernel(const float* __restrict__ W1, const float* __restrict__ b1,
                              const float* __restrict__ W2, float* __restrict__ wp)
{
    for (int i = blockIdx.x*256 + threadIdx.x; i < 3*PK_LAY; i += gridDim.x*256) {
        const int L = i / PK_LAY, r = i % PK_LAY;
        float v;
        if (r < PK_WB) {                    // wx[o][20] = W1a(16) | b1 | w_dist | pad2
            const int o = r / 20, c = r % 20;
            if      (c < 16)  v = W1[(L*HH + o)*HH + c];
            else if (c == 16) v = b1[L*HH + o];
            else if (c == 17) v = W1[(L*HH + o)*HH + 32];
            else              v = 0.0f;
        } else if (r < PK_WT) {             // wb[o][16] = W1[o][16..31]
            const int q = r - PK_WB, o = q / 16, c = q % 16;
            v = W1[(L*HH + o)*HH + 16 + c];
        } else {                            // wt[o][16] = W2[d][o] transposed
            const int q = r - PK_WT, o = q / 16, d = q % 16;
            v = W2[(L*DD + d)*HH + o];
        }
        wp[i] = v;
    }
}

// ---------------- MP: 8 lanes/point, 2 k's/lane, rolled o-loop ----------------
#define DOT16(res, A, q0, q1, q2, q3)                                   \
    res = fmaf(A[0],  q0.x, res); res = fmaf(A[1],  q0.y, res);         \
    res = fmaf(A[2],  q0.z, res); res = fmaf(A[3],  q0.w, res);         \
    res = fmaf(A[4],  q1.x, res); res = fmaf(A[5],  q1.y, res);         \
    res = fmaf(A[6],  q1.z, res); res = fmaf(A[7],  q1.w, res);         \
    res = fmaf(A[8],  q2.x, res); res = fmaf(A[9],  q2.y, res);         \
    res = fmaf(A[10], q2.z, res); res = fmaf(A[11], q2.w, res);         \
    res = fmaf(A[12], q3.x, res); res = fmaf(A[13], q3.y, res);         \
    res = fmaf(A[14], q3.z, res); res = fmaf(A[15], q3.w, res);

__global__ __launch_bounds__(256) void mp_kernel(
    const int*   __restrict__ nidx, const float* __restrict__ nd2,
    const float* __restrict__ yat,  const float* __restrict__ wpack,
    const float* __restrict__ b2,
    const float* __restrict__ gnw, const float* __restrict__ gnb,
    float* __restrict__ out)
{
    const int g  = blockIdx.x * 256 + threadIdx.x;
    const int n  = g >> 3;
    const int kl = g & 7;

    const int2   iv = *reinterpret_cast<const int2*>  (nidx + n*KK + kl*2);
    const float2 dv = *reinterpret_cast<const float2*>(nd2  + n*KK + kl*2);

    float at0[DD], at1[DD];
    {
        const float4* p0 = reinterpret_cast<const float4*>(yat + (long)iv.x*DD);
        const float4* p1 = reinterpret_cast<const float4*>(yat + (long)iv.y*DD);
        const float4 a = p0[0], b = p0[1], c = p0[2], d = p0[3];
        const float4 e = p1[0], f = p1[1], h = p1[2], i = p1[3];
        at0[0]=a.x; at0[1]=a.y; at0[2]=a.z; at0[3]=a.w;
        at0[4]=b.x; at0[5]=b.y; at0[6]=b.z; at0[7]=b.w;
        at0[8]=c.x; at0[9]=c.y; at0[10]=c.z; at0[11]=c.w;
        at0[12]=d.x; at0[13]=d.y; at0[14]=d.z; at0[15]=d.w;
        at1[0]=e.x; at1[1]=e.y; at1[2]=e.z; at1[3]=e.w;
        at1[4]=f.x; at1[5]=f.y; at1[6]=f.z; at1[7]=f.w;
        at1[8]=h.x; at1[9]=h.y; at1[10]=h.z; at1[11]=h.w;
        at1[12]=i.x; at1[13]=i.y; at1[14]=i.z; at1[15]=i.w;
    }

    float pe[DD];
    #pragma unroll
    for (int h = 0; h < DD; ++h) pe[h] = 1.0f;

    for (int L = 0; L < 3; ++L) {
        const float* wp = wpack + L*PK_LAY;

        float msg[DD];
        {
            const float4* bq = reinterpret_cast<const float4*>(b2 + L*DD);
            const float4 q0 = bq[0], q1 = bq[1], q2 = bq[2], q3 = bq[3];
            msg[0]=2.f*q0.x; msg[1]=2.f*q0.y; msg[2]=2.f*q0.z; msg[3]=2.f*q0.w;
            msg[4]=2.f*q1.x; msg[5]=2.f*q1.y; msg[6]=2.f*q1.z; msg[7]=2.f*q1.w;
            msg[8]=2.f*q2.x; msg[9]=2.f*q2.y; msg[10]=2.f*q2.z; msg[11]=2.f*q2.w;
            msg[12]=2.f*q3.x; msg[13]=2.f*q3.y; msg[14]=2.f*q3.z; msg[15]=2.f*q3.w;
        }

        #pragma unroll 1
        for (int o = 0; o < HH; ++o) {
            const float4* wx = reinterpret_cast<const float4*>(wp + PK_WX + o*20);
            const float4 x0 = wx[0], x1 = wx[1], x2 = wx[2], x3 = wx[3], x4 = wx[4];
            const float4* wb = reinterpret_cast<const float4*>(wp + PK_WB + o*16);
            const float4 y0 = wb[0], y1 = wb[1], y2 = wb[2], y3 = wb[3];
            const float4* wt = reinterpret_cast<const float4*>(wp + PK_WT + o*16);
            const float4 t0 = wt[0], t1 = wt[1], t2 = wt[2], t3 = wt[3];

            float bas = x4.x;                 // b1[o]
            DOT16(bas, pe, x0, x1, x2, x3);   // + pe . W1a[o]

            float u0 = fmaf(dv.x, x4.y, bas); // + dist*W1[o][32]
            DOT16(u0, at0, y0, y1, y2, y3);
            float u1 = fmaf(dv.y, x4.y, bas);
            DOT16(u1, at1, y0, y1, y2, y3);

            const float hs = fmaxf(u0, SLOPE*u0) + fmaxf(u1, SLOPE*u1);

            msg[0]  = fmaf(hs, t0.x, msg[0]);  msg[1]  = fmaf(hs, t0.y, msg[1]);
            msg[2]  = fmaf(hs, t0.z, msg[2]);  msg[3]  = fmaf(hs, t0.w, msg[3]);
            msg[4]  = fmaf(hs, t1.x, msg[4]);  msg[5]  = fmaf(hs, t1.y, msg[5]);
            msg[6]  = fmaf(hs, t1.z, msg[6]);  msg[7]  = fmaf(hs, t1.w, msg[7]);
            msg[8]  = fmaf(hs, t2.x, msg[8]);  msg[9]  = fmaf(hs, t2.y, msg[9]);
            msg[10] = fmaf(hs, t2.z, msg[10]); msg[11] = fmaf(hs, t2.w, msg[11]);
            msg[12] = fmaf(hs, t3.x, msg[12]); msg[13] = fmaf(hs, t3.y, msg[13]);
            msg[14] = fmaf(hs, t3.z, msg[14]); msg[15] = fmaf(hs, t3.w, msg[15]);
        }

        // sum partial msg over the 8 lanes of this point
        #pragma unroll
        for (int o = 0; o < DD; ++o) {
            msg[o] += __shfl_xor(msg[o], 1);
            msg[o] += __shfl_xor(msg[o], 2);
            msg[o] += __shfl_xor(msg[o], 4);
        }

        // GroupNorm(2,16) + leaky + residual (redundant per lane)
        const float4* gw = reinterpret_cast<const float4*>(gnw + L*DD);
        const float4* gb = reinterpret_cast<const float4*>(gnb + L*DD);
        const float4 gw0 = gw[0], gw1 = gw[1], gw2 = gw[2], gw3 = gw[3];
        const float4 gb0 = gb[0], gb1 = gb[1], gb2 = gb[2], gb3 = gb[3];
        const float gwa[DD] = { gw0.x,gw0.y,gw0.z,gw0.w, gw1.x,gw1.y,gw1.z,gw1.w,
                                gw2.x,gw2.y,gw2.z,gw2.w, gw3.x,gw3.y,gw3.z,gw3.w };
        const float gba[DD] = { gb0.x,gb0.y,gb0.z,gb0.w, gb1.x,gb1.y,gb1.z,gb1.w,
                                gb2.x,gb2.y,gb2.z,gb2.w, gb3.x,gb3.y,gb3.z,gb3.w };
        #pragma unroll
        for (int grp = 0; grp < 2; ++grp) {
            float mu = 0.0f;
            #pragma unroll
            for (int j = 0; j < 8; ++j) mu += msg[grp*8 + j];
            mu *= 0.125f;
            float var = 0.0f;
            #pragma unroll
            for (int j = 0; j < 8; ++j) { const float d = msg[grp*8 + j] - mu; var = fmaf(d, d, var); }
            var *= 0.125f;
            const float rs = rsqrtf(var + EPSGN);
            #pragma unroll
            for (int j = 0; j < 8; ++j) {
                const int c = grp*8 + j;
                const float v = (msg[c] - mu) * rs * gwa[c] + gba[c];
                pe[c] += fmaxf(v, SLOPE * v);
            }
        }
    }

    if (kl == 0) {
        float4* op = reinterpret_cast<float4*>(out + (long)n*DD);
        op[0] = make_float4(pe[0],  pe[1],  pe[2],  pe[3]);
        op[1] = make_float4(pe[4],  pe[5],  pe[6],  pe[7]);
        op[2] = make_float4(pe[8],  pe[9],  pe[10], pe[11]);
        op[3] = make_float4(pe[12], pe[13], pe[14], pe[15]);
    }
}

extern "C" void kernel_launch(void* const* d_in, const int* in_sizes, int n_in,
                              void* d_out, int out_size, void* d_ws, size_t ws_size,
                              hipStream_t stream) {
    const float* x   = (const float*)d_in[0];
    const float* y   = (const float*)d_in[1];
    const float* yat = (const float*)d_in[2];
    const int*   xb  = (const int*)  d_in[3];
    const int*   yb  = (const int*)  d_in[4];
    const float* W1  = (const float*)d_in[5];
    const float* b1  = (const float*)d_in[6];
    const float* W2  = (const float*)d_in[7];
    const float* b2  = (const float*)d_in[8];
    const float* gnw = (const float*)d_in[9];
    const float* gnb = (const float*)d_in[10];
    float* out = (float*)d_out;

    int*   ws_idx = (int*)d_ws;
    float* ws_d2  = (float*)((char*)d_ws + (size_t)N_PTS*KK*sizeof(int));
    float* wpack  = (float*)((char*)d_ws + 2*(size_t)N_PTS*KK*sizeof(int));

    repack_kernel<<<8, 256, 0, stream>>>(W1, b1, W2, wpack);
    knn_kernel<<<N_PTS/4, 256, 0, stream>>>(x, y, xb, yb, ws_idx, ws_d2);
    mp_kernel<<<(N_PTS*8)/256, 256, 0, stream>>>(
        ws_idx, ws_d2, yat, wpack, b2, gnw, gnb, out);
}

// Round 5
// 124.779 us; speedup vs baseline: 6.8096x; 1.5367x over previous
//
#include <hip/hip_runtime.h>
#include <math.h>

#define N_PTS 20000
#define M_ATM 8000
#define DD    16
#define KK    16
#define HH    33
#define EPSGN 1e-5f
#define SLOPE 0.2f
#define SLOTS 36   // 36*64 = 2304 candidates/wave >= max batch segment
#define ALL1  0xFFFFFFFFFFFFFFFFull

// packed layout per layer (floats): wx[33][20] | wb[33][16] | wt[33][16]
#define PK_WX   0
#define PK_WB   660
#define PK_WT   1188
#define PK_LAY  1716

// ---------------- KNN: one WAVE per point, packed-u64 selection ----------------
// key = (f64-bits of d^2, low 12 bits replaced by candidate offset).
// Non-negative doubles order as unsigned -> u64 min == (min d2, then min index).
__global__ __launch_bounds__(256) void knn_kernel(
    const float* __restrict__ x, const float* __restrict__ y,
    const int* __restrict__ xb, const int* __restrict__ yb,
    int* __restrict__ out_idx, float* __restrict__ out_d2)
{
    const int wv   = threadIdx.x >> 6;
    const int lane = threadIdx.x & 63;
    const int n    = blockIdx.x * 4 + wv;

    const double x0 = (double)x[n*3+0], x1 = (double)x[n*3+1], x2 = (double)x[n*3+2];
    const int b = xb[n];

    int lo, hi;
    { int l = 0, r = M_ATM; while (l < r) { int m = (l+r) >> 1; if (yb[m] <  b) l = m+1; else r = m; } lo = l; }
    { int l = 0, r = M_ATM; while (l < r) { int m = (l+r) >> 1; if (yb[m] <= b) l = m+1; else r = m; } hi = l; }

    // per-lane sorted top-4 packed keys (ascending); ALL1 = +inf sentinel
    unsigned long long m0 = ALL1, m1 = ALL1, m2 = ALL1, m3 = ALL1;
    #pragma unroll
    for (int s = 0; s < SLOTS; ++s) {
        const int j = lo + lane + 64*s;
        if (j < hi) {
            const double d0 = x0 - (double)y[j*3+0];
            const double d1 = x1 - (double)y[j*3+1];
            const double d2 = x2 - (double)y[j*3+2];
            const double dd = fma(d0, d0, fma(d1, d1, d2*d2));
            const unsigned long long kb =
                ((unsigned long long)__double_as_longlong(dd) & ~0xFFFull)
                | (unsigned long long)(lane + 64*s);
            if (kb < m3) {                       // fast reject
                if      (kb < m0) { m3 = m2; m2 = m1; m1 = m0; m0 = kb; }
                else if (kb < m1) { m3 = m2; m2 = m1; m1 = kb; }
                else if (kb < m2) { m3 = m2; m2 = kb; }
                else              { m3 = kb; }
            }
        }
    }

    unsigned long long cmask = 0ull;   // consumed slots (for rare rebuild)
    unsigned long long res_key = 0ull;

    #define SWZ_MIN(OFF) {                                                    \
        const unsigned int l32 = (unsigned int)bv;                            \
        const unsigned int h32 = (unsigned int)(bv >> 32);                    \
        const unsigned int ol = (unsigned int)__builtin_amdgcn_ds_swizzle((int)l32, OFF); \
        const unsigned int oh = (unsigned int)__builtin_amdgcn_ds_swizzle((int)h32, OFF); \
        const unsigned long long ov = ((unsigned long long)oh << 32) | ol;    \
        bv = (ov < bv) ? ov : bv; }

    for (int r = 0; r < KK; ++r) {
        unsigned long long bv = m0;
        SWZ_MIN(0x041F)   // xor 1
        SWZ_MIN(0x081F)   // xor 2
        SWZ_MIN(0x101F)   // xor 4
        SWZ_MIN(0x201F)   // xor 8
        SWZ_MIN(0x401F)   // xor 16  -> each 32-half holds its min in all lanes
        const unsigned int bl = (unsigned int)bv;
        const unsigned int bh = (unsigned int)(bv >> 32);
        const unsigned long long k0 =
            ((unsigned long long)(unsigned int)__builtin_amdgcn_readlane((int)bh, 0)  << 32)
            | (unsigned int)__builtin_amdgcn_readlane((int)bl, 0);
        const unsigned long long k1 =
            ((unsigned long long)(unsigned int)__builtin_amdgcn_readlane((int)bh, 32) << 32)
            | (unsigned int)__builtin_amdgcn_readlane((int)bl, 32);
        const unsigned long long win = (k0 < k1) ? k0 : k1;   // wave-uniform

        res_key = (lane == r) ? win : res_key;

        const int woff = (int)(win & 0xFFFull);
        if (lane == (woff & 63)) {               // winner lane pops its head
            cmask |= 1ull << (woff >> 6);
            m0 = m1; m1 = m2; m2 = m3; m3 = ALL1;
            if (m0 == ALL1) {
                // rare rebuild (a lane won 4+ times): rescan excluding consumed
                #pragma unroll 1
                for (int s = 0; s < SLOTS; ++s) {
                    const int j = lo + lane + 64*s;
                    if (j < hi && !((cmask >> s) & 1ull)) {
                        const double d0 = x0 - (double)y[j*3+0];
                        const double d1 = x1 - (double)y[j*3+1];
                        const double d2 = x2 - (double)y[j*3+2];
                        const double dd = fma(d0, d0, fma(d1, d1, d2*d2));
                        const unsigned long long kb =
                            ((unsigned long long)__double_as_longlong(dd) & ~0xFFFull)
                            | (unsigned long long)(lane + 64*s);
                        if (kb < m3) {
                            if      (kb < m0) { m3 = m2; m2 = m1; m1 = m0; m0 = kb; }
                            else if (kb < m1) { m3 = m2; m2 = m1; m1 = kb; }
                            else if (kb < m2) { m3 = m2; m2 = kb; }
                            else              { m3 = kb; }
                        }
                    }
                }
            }
        }
    }
    #undef SWZ_MIN

    if (lane < KK) {
        out_idx[n*KK + lane] = lo + (int)(res_key & 0xFFFull);
        out_d2 [n*KK + lane] =
            (float)__longlong_as_double((long long)(res_key & ~0xFFFull));
    }
}

// ---------------- weight repack into 16B-aligned rows ----------------
__global__ void repack_kernel(const float* __restrict__ W1, const float* __restrict__ b1,
                              const float* __restrict__ W2, float* __restrict__ wp)
{
    for (int i = blockIdx.x*256 + threadIdx.x; i < 3*PK_LAY; i += gridDim.x*256) {
        const int L = i / PK_LAY, r = i % PK_LAY;
        float v;
        if (r < PK_WB) {                    // wx[o][20] = W1a(16) | b1 | w_dist | pad2
            const int o = r / 20, c = r % 20;
            if      (c < 16)  v = W1[(L*HH + o)*HH + c];
            else if (c == 16) v = b1[L*HH + o];
            else if (c == 17) v = W1[(L*HH + o)*HH + 32];
            else              v = 0.0f;
        } else if (r < PK_WT) {             // wb[o][16] = W1[o][16..31]
            const int q = r - PK_WB, o = q / 16, c = q % 16;
            v = W1[(L*HH + o)*HH + 16 + c];
        } else {                            // wt[o][16] = W2[d][o] transposed
            const int q = r - PK_WT, o = q / 16, d = q % 16;
            v = W2[(L*DD + d)*HH + o];
        }
        wp[i] = v;
    }
}

// ---------------- MP: 8 lanes/point, 2 k's/lane, rolled o-loop ----------------
#define DOT16(res, A, q0, q1, q2, q3)                                   \
    res = fmaf(A[0],  q0.x, res); res = fmaf(A[1],  q0.y, res);         \
    res = fmaf(A[2],  q0.z, res); res = fmaf(A[3],  q0.w, res);         \
    res = fmaf(A[4],  q1.x, res); res = fmaf(A[5],  q1.y, res);         \
    res = fmaf(A[6],  q1.z, res); res = fmaf(A[7],  q1.w, res);         \
    res = fmaf(A[8],  q2.x, res); res = fmaf(A[9],  q2.y, res);         \
    res = fmaf(A[10], q2.z, res); res = fmaf(A[11], q2.w, res);         \
    res = fmaf(A[12], q3.x, res); res = fmaf(A[13], q3.y, res);         \
    res = fmaf(A[14], q3.z, res); res = fmaf(A[15], q3.w, res);

__global__ __launch_bounds__(256) void mp_kernel(
    const int*   __restrict__ nidx, const float* __restrict__ nd2,
    const float* __restrict__ yat,  const float* __restrict__ wpack,
    const float* __restrict__ b2,
    const float* __restrict__ gnw, const float* __restrict__ gnb,
    float* __restrict__ out)
{
    const int g  = blockIdx.x * 256 + threadIdx.x;
    const int n  = g >> 3;
    const int kl = g & 7;

    const int2   iv = *reinterpret_cast<const int2*>  (nidx + n*KK + kl*2);
    const float2 dv = *reinterpret_cast<const float2*>(nd2  + n*KK + kl*2);

    float at0[DD], at1[DD];
    {
        const float4* p0 = reinterpret_cast<const float4*>(yat + (long)iv.x*DD);
        const float4* p1 = reinterpret_cast<const float4*>(yat + (long)iv.y*DD);
        const float4 a = p0[0], b = p0[1], c = p0[2], d = p0[3];
        const float4 e = p1[0], f = p1[1], h = p1[2], i = p1[3];
        at0[0]=a.x; at0[1]=a.y; at0[2]=a.z; at0[3]=a.w;
        at0[4]=b.x; at0[5]=b.y; at0[6]=b.z; at0[7]=b.w;
        at0[8]=c.x; at0[9]=c.y; at0[10]=c.z; at0[11]=c.w;
        at0[12]=d.x; at0[13]=d.y; at0[14]=d.z; at0[15]=d.w;
        at1[0]=e.x; at1[1]=e.y; at1[2]=e.z; at1[3]=e.w;
        at1[4]=f.x; at1[5]=f.y; at1[6]=f.z; at1[7]=f.w;
        at1[8]=h.x; at1[9]=h.y; at1[10]=h.z; at1[11]=h.w;
        at1[12]=i.x; at1[13]=i.y; at1[14]=i.z; at1[15]=i.w;
    }

    float pe[DD];
    #pragma unroll
    for (int h = 0; h < DD; ++h) pe[h] = 1.0f;

    for (int L = 0; L < 3; ++L) {
        const float* wp = wpack + L*PK_LAY;

        float msg[DD];
        {
            const float4* bq = reinterpret_cast<const float4*>(b2 + L*DD);
            const float4 q0 = bq[0], q1 = bq[1], q2 = bq[2], q3 = bq[3];
            msg[0]=2.f*q0.x; msg[1]=2.f*q0.y; msg[2]=2.f*q0.z; msg[3]=2.f*q0.w;
            msg[4]=2.f*q1.x; msg[5]=2.f*q1.y; msg[6]=2.f*q1.z; msg[7]=2.f*q1.w;
            msg[8]=2.f*q2.x; msg[9]=2.f*q2.y; msg[10]=2.f*q2.z; msg[11]=2.f*q2.w;
            msg[12]=2.f*q3.x; msg[13]=2.f*q3.y; msg[14]=2.f*q3.z; msg[15]=2.f*q3.w;
        }

        #pragma unroll 1
        for (int o = 0; o < HH; ++o) {
            const float4* wx = reinterpret_cast<const float4*>(wp + PK_WX + o*20);
            const float4 x0 = wx[0], x1 = wx[1], x2 = wx[2], x3 = wx[3], x4 = wx[4];
            const float4* wb = reinterpret_cast<const float4*>(wp + PK_WB + o*16);
            const float4 y0 = wb[0], y1 = wb[1], y2 = wb[2], y3 = wb[3];
            const float4* wt = reinterpret_cast<const float4*>(wp + PK_WT + o*16);
            const float4 t0 = wt[0], t1 = wt[1], t2 = wt[2], t3 = wt[3];

            float bas = x4.x;                 // b1[o]
            DOT16(bas, pe, x0, x1, x2, x3);   // + pe . W1a[o]

            float u0 = fmaf(dv.x, x4.y, bas); // + dist*W1[o][32]
            DOT16(u0, at0, y0, y1, y2, y3);
            float u1 = fmaf(dv.y, x4.y, bas);
            DOT16(u1, at1, y0, y1, y2, y3);

            const float hs = fmaxf(u0, SLOPE*u0) + fmaxf(u1, SLOPE*u1);

            msg[0]  = fmaf(hs, t0.x, msg[0]);  msg[1]  = fmaf(hs, t0.y, msg[1]);
            msg[2]  = fmaf(hs, t0.z, msg[2]);  msg[3]  = fmaf(hs, t0.w, msg[3]);
            msg[4]  = fmaf(hs, t1.x, msg[4]);  msg[5]  = fmaf(hs, t1.y, msg[5]);
            msg[6]  = fmaf(hs, t1.z, msg[6]);  msg[7]  = fmaf(hs, t1.w, msg[7]);
            msg[8]  = fmaf(hs, t2.x, msg[8]);  msg[9]  = fmaf(hs, t2.y, msg[9]);
            msg[10] = fmaf(hs, t2.z, msg[10]); msg[11] = fmaf(hs, t2.w, msg[11]);
            msg[12] = fmaf(hs, t3.x, msg[12]); msg[13] = fmaf(hs, t3.y, msg[13]);
            msg[14] = fmaf(hs, t3.z, msg[14]); msg[15] = fmaf(hs, t3.w, msg[15]);
        }

        // sum partial msg over the 8 lanes of this point
        #pragma unroll
        for (int o = 0; o < DD; ++o) {
            msg[o] += __shfl_xor(msg[o], 1);
            msg[o] += __shfl_xor(msg[o], 2);
            msg[o] += __shfl_xor(msg[o], 4);
        }

        // GroupNorm(2,16) + leaky + residual (redundant per lane)
        const float4* gw = reinterpret_cast<const float4*>(gnw + L*DD);
        const float4* gb = reinterpret_cast<const float4*>(gnb + L*DD);
        const float4 gw0 = gw[0], gw1 = gw[1], gw2 = gw[2], gw3 = gw[3];
        const float4 gb0 = gb[0], gb1 = gb[1], gb2 = gb[2], gb3 = gb[3];
        const float gwa[DD] = { gw0.x,gw0.y,gw0.z,gw0.w, gw1.x,gw1.y,gw1.z,gw1.w,
                                gw2.x,gw2.y,gw2.z,gw2.w, gw3.x,gw3.y,gw3.z,gw3.w };
        const float gba[DD] = { gb0.x,gb0.y,gb0.z,gb0.w, gb1.x,gb1.y,gb1.z,gb1.w,
                                gb2.x,gb2.y,gb2.z,gb2.w, gb3.x,gb3.y,gb3.z,gb3.w };
        #pragma unroll
        for (int grp = 0; grp < 2; ++grp) {
            float mu = 0.0f;
            #pragma unroll
            for (int j = 0; j < 8; ++j) mu += msg[grp*8 + j];
            mu *= 0.125f;
            float var = 0.0f;
            #pragma unroll
            for (int j = 0; j < 8; ++j) { const float d = msg[grp*8 + j] - mu; var = fmaf(d, d, var); }
            var *= 0.125f;
            const float rs = rsqrtf(var + EPSGN);
            #pragma unroll
            for (int j = 0; j < 8; ++j) {
                const int c = grp*8 + j;
                const float v = (msg[c] - mu) * rs * gwa[c] + gba[c];
                pe[c] += fmaxf(v, SLOPE * v);
            }
        }
    }

    if (kl == 0) {
        float4* op = reinterpret_cast<float4*>(out + (long)n*DD);
        op[0] = make_float4(pe[0],  pe[1],  pe[2],  pe[3]);
        op[1] = make_float4(pe[4],  pe[5],  pe[6],  pe[7]);
        op[2] = make_float4(pe[8],  pe[9],  pe[10], pe[11]);
        op[3] = make_float4(pe[12], pe[13], pe[14], pe[15]);
    }
}

extern "C" void kernel_launch(void* const* d_in, const int* in_sizes, int n_in,
                              void* d_out, int out_size, void* d_ws, size_t ws_size,
                              hipStream_t stream) {
    const float* x   = (const float*)d_in[0];
    const float* y   = (const float*)d_in[1];
    const float* yat = (const float*)d_in[2];
    const int*   xb  = (const int*)  d_in[3];
    const int*   yb  = (const int*)  d_in[4];
    const float* W1  = (const float*)d_in[5];
    const float* b1  = (const float*)d_in[6];
    const float* W2  = (const float*)d_in[7];
    const float* b2  = (const float*)d_in[8];
    const float* gnw = (const float*)d_in[9];
    const float* gnb = (const float*)d_in[10];
    float* out = (float*)d_out;

    int*   ws_idx = (int*)d_ws;
    float* ws_d2  = (float*)((char*)d_ws + (size_t)N_PTS*KK*sizeof(int));
    float* wpack  = (float*)((char*)d_ws + 2*(size_t)N_PTS*KK*sizeof(int));

    repack_kernel<<<8, 256, 0, stream>>>(W1, b1, W2, wpack);
    knn_kernel<<<N_PTS/4, 256, 0, stream>>>(x, y, xb, yb, ws_idx, ws_d2);
    mp_kernel<<<(N_PTS*8)/256, 256, 0, stream>>>(
        ws_idx, ws_d2, yat, wpack, b2, gnw, gnb, out);
}